// Round 2
// baseline (518.660 us; speedup 1.0000x reference)
//
#include <hip/hip_runtime.h>
#include <stdint.h>

#define D_DIM 256

typedef unsigned short ushort_t;
typedef __attribute__((ext_vector_type(8))) short bf16x8;   // 8 bf16 = 4 VGPRs
typedef __attribute__((ext_vector_type(4))) float f32x4;

__device__ __forceinline__ unsigned short f2bf(float f) {
  union { float f; unsigned u; } x; x.f = f;
  unsigned r = x.u + 0x7FFFu + ((x.u >> 16) & 1u);  // round-nearest-even
  return (unsigned short)(r >> 16);
}

// async global->LDS, 16B per lane. LDS dest = wave-uniform base + lane*16.
__device__ __forceinline__ void g2l16(const void* g, void* l) {
  __builtin_amdgcn_global_load_lds(
      (__attribute__((address_space(1))) void*)(uintptr_t)g,
      (__attribute__((address_space(3))) void*)(unsigned)(uintptr_t)l,
      16, 0, 0);
}

// ---------------- prep: cast fp32 -> bf16 rows + row norms ----------------
__global__ __launch_bounds__(256) void
prep_cast(const float* __restrict__ G, const float* __restrict__ P,
          ushort_t* __restrict__ Tb, float* __restrict__ nrm, int Bn)
{
  const int r = blockIdx.x, t = threadIdx.x;
  const float* src = (r < Bn) ? (G + (size_t)r * D_DIM)
                              : (P + (size_t)(r - Bn) * D_DIM);
  float v = src[t];
  Tb[(size_t)r * D_DIM + t] = f2bf(v);
  float s = v * v;
  #pragma unroll
  for (int o = 32; o > 0; o >>= 1) s += __shfl_down(s, o, 64);
  __shared__ float red[4];
  if ((t & 63) == 0) red[t >> 6] = s;
  __syncthreads();
  if (t == 0) nrm[r] = red[0] + red[1] + red[2] + red[3];
}

// ---------------- prep: transpose Tb (Ttot x 256) -> TT (256 x Ttot) ----------------
__global__ __launch_bounds__(256) void
prep_transpose(const ushort_t* __restrict__ Tb, ushort_t* __restrict__ TT, int Ttot)
{
  __shared__ ushort_t Ts[64][72];
  const int t = threadIdx.x;
  const int j0 = blockIdx.x * 64, d0 = blockIdx.y * 64;
  #pragma unroll
  for (int q = 0; q < 16; q++) {
    int idx = q * 256 + t;
    int jr = idx >> 6, dc = idx & 63;
    Ts[dc][jr] = Tb[(size_t)(j0 + jr) * D_DIM + d0 + dc];
  }
  __syncthreads();
  #pragma unroll
  for (int q = 0; q < 16; q++) {
    int idx = q * 256 + t;
    int dr = idx >> 6, jc = idx & 63;
    TT[(size_t)(d0 + dr) * Ttot + j0 + jc] = Ts[dr][jc];
  }
}

// ---------------- phase 1 (one j-quarter): S = G @ Tq^T -> K, rowsums ----------------
// 128x128 tile, BK=32, 4 waves in 2x2, each wave 64x64 = 4x4 mfma tiles.
// Writes Kq (8192 x QW bf16, row stride QW) and atomically accumulates rowsums into S.
#define QW 4096
__global__ __launch_bounds__(256) void
phase1_kernel(const ushort_t* __restrict__ Tb, const float* __restrict__ nrm,
              ushort_t* __restrict__ Kq, float* __restrict__ S,
              int j_origin, int diagHalf)
{
  __shared__ ushort_t Asm[128 * 32];
  __shared__ ushort_t Bsm[128 * 32];
  const int t = threadIdx.x;
  const int w = t >> 6, lane = t & 63;
  const int wr = w >> 1, wc = w & 1;
  const int i0 = blockIdx.x * 128;
  const int jloc0 = blockIdx.y * 128;
  const int jglob0 = j_origin + jloc0;

  f32x4 acc[4][4];
  #pragma unroll
  for (int m = 0; m < 4; m++)
    #pragma unroll
    for (int n = 0; n < 4; n++) acc[m][n] = (f32x4)0.f;

  const int srow = t >> 2;
  const int sch  = (t & 3) * 8;
  const ushort_t* Ag = Tb + (size_t)(i0 + srow) * D_DIM + sch;
  const ushort_t* Bg = Tb + (size_t)(jglob0 + srow) * D_DIM + sch;
  ushort_t* Al = Asm + t * 8;
  ushort_t* Bl = Bsm + t * 8;

  const int arow = wr * 64 + (lane & 15);
  const int brow = wc * 64 + (lane & 15);
  const int kc = (lane >> 4) * 8;

  for (int k0 = 0; k0 < D_DIM; k0 += 32) {
    g2l16(Ag + k0, Al);
    g2l16(Ag + 64 * D_DIM + k0, Al + 64 * 32);
    g2l16(Bg + k0, Bl);
    g2l16(Bg + 64 * D_DIM + k0, Bl + 64 * 32);
    __syncthreads();
    bf16x8 af[4], bff[4];
    #pragma unroll
    for (int m = 0; m < 4; m++) af[m]  = *(const bf16x8*)&Asm[(arow + m * 16) * 32 + kc];
    #pragma unroll
    for (int n = 0; n < 4; n++) bff[n] = *(const bf16x8*)&Bsm[(brow + n * 16) * 32 + kc];
    #pragma unroll
    for (int m = 0; m < 4; m++)
      #pragma unroll
      for (int n = 0; n < 4; n++)
        acc[m][n] = __builtin_amdgcn_mfma_f32_16x16x32_bf16(af[m], bff[n], acc[m][n], 0, 0, 0);
    __syncthreads();
  }

  // epilogue: sq = |g|^2 + |t|^2 - 2 dot ; k = exp(-sqrt(clip)/20); diag -> 0
  const int g = lane >> 4, c = lane & 15;
  #pragma unroll
  for (int m = 0; m < 4; m++) {
    #pragma unroll
    for (int reg = 0; reg < 4; reg++) {
      const int i = i0 + wr * 64 + m * 16 + g * 4 + reg;
      const float ni = nrm[i];
      float rs = 0.f;
      #pragma unroll
      for (int n = 0; n < 4; n++) {
        const int jloc = jloc0 + wc * 64 + n * 16 + c;
        const int jglob = j_origin + jloc;
        float sq = ni + nrm[jglob] - 2.f * acc[m][n][reg];
        float dd = sqrtf(fmaxf(sq, 0.f));
        float kv = (diagHalf && (i == jglob)) ? 0.f : __expf(dd * -0.05f);
        Kq[(size_t)i * QW + jloc] = f2bf(kv);
        rs += kv;
      }
      rs += __shfl_xor(rs, 1, 64);
      rs += __shfl_xor(rs, 2, 64);
      rs += __shfl_xor(rs, 4, 64);
      rs += __shfl_xor(rs, 8, 64);
      if (c == 0) atomicAdd(&S[i], rs);
    }
  }
}

// ---------------- phase 2 (one j-quarter): dst += scale_i * (Kq @ Tq) ----------------
// block = 64 rows x 256 cols (full D). grid.y = 4 splits of the quarter's K-range.
__global__ __launch_bounds__(256) void
phase2_kernel(const ushort_t* __restrict__ Kq, const ushort_t* __restrict__ TT,
              const float* __restrict__ rowscale, float* __restrict__ dst,
              int j_origin, int Ttot)
{
  __shared__ ushort_t Wsm[64 * 32];
  __shared__ ushort_t Tsm[256 * 32];
  const int t = threadIdx.x;
  const int w = t >> 6, lane = t & 63;
  const int i0 = blockIdx.x * 64;
  const int KLEN = QW / 4;                 // 1024
  const int jloc_base = blockIdx.y * KLEN;

  f32x4 acc[4][4];
  #pragma unroll
  for (int m = 0; m < 4; m++)
    #pragma unroll
    for (int n = 0; n < 4; n++) acc[m][n] = (f32x4)0.f;

  const int srow = t >> 2;
  const int sch  = (t & 3) * 8;
  const ushort_t* Wg = Kq + (size_t)(i0 + srow) * QW + jloc_base + sch;
  const ushort_t* Tg = TT + (size_t)srow * Ttot + j_origin + jloc_base + sch;
  ushort_t* Wl = Wsm + t * 8;
  ushort_t* Tl = Tsm + t * 8;

  const int arow = lane & 15;
  const int kc = (lane >> 4) * 8;

  for (int k0 = 0; k0 < KLEN; k0 += 32) {
    g2l16(Wg + k0, Wl);
    #pragma unroll
    for (int q = 0; q < 4; q++)
      g2l16(Tg + (size_t)q * 64 * Ttot + k0, Tl + q * 64 * 32);
    __syncthreads();
    bf16x8 af[4], bff[4];
    #pragma unroll
    for (int m = 0; m < 4; m++) af[m]  = *(const bf16x8*)&Wsm[(arow + m * 16) * 32 + kc];
    #pragma unroll
    for (int n = 0; n < 4; n++) bff[n] = *(const bf16x8*)&Tsm[(w * 64 + arow + n * 16) * 32 + kc];
    #pragma unroll
    for (int m = 0; m < 4; m++)
      #pragma unroll
      for (int n = 0; n < 4; n++)
        acc[m][n] = __builtin_amdgcn_mfma_f32_16x16x32_bf16(af[m], bff[n], acc[m][n], 0, 0, 0);
    __syncthreads();
  }

  const int g = lane >> 4, c = lane & 15;
  #pragma unroll
  for (int m = 0; m < 4; m++) {
    #pragma unroll
    for (int reg = 0; reg < 4; reg++) {
      const int i = i0 + m * 16 + g * 4 + reg;
      const float sc = rowscale ? rowscale[i] : 1.0f;
      #pragma unroll
      for (int n = 0; n < 4; n++) {
        const int d = w * 64 + n * 16 + c;
        atomicAdd(&dst[(size_t)i * D_DIM + d], sc * acc[m][n][reg]);
      }
    }
  }
}

// ---------------- combine: out -= sp * Mg ----------------
__global__ __launch_bounds__(256) void
combine_kernel(float* __restrict__ out, const float* __restrict__ Mg,
               const float* __restrict__ sp)
{
  const int i = blockIdx.x, t = threadIdx.x;
  const size_t idx = (size_t)i * D_DIM + t;
  out[idx] -= sp[i] * Mg[idx];
}

extern "C" void kernel_launch(void* const* d_in, const int* in_sizes, int n_in,
                              void* d_out, int out_size, void* d_ws, size_t ws_size,
                              hipStream_t stream)
{
  const float* G = (const float*)d_in[0];
  const float* P = (const float*)d_in[1];
  const int Bn = in_sizes[0] / D_DIM;   // 8192
  const int Xn = in_sizes[1] / D_DIM;   // 8192
  const int Ttot = Bn + Xn;             // 16384

  float* out = (float*)d_out;
  hipMemsetAsync(out, 0, (size_t)out_size * sizeof(float), stream);

  // workspace layout (~88.2 MiB total)
  uint8_t* ws = (uint8_t*)d_ws;
  size_t off = 0;
  ushort_t* Tb = (ushort_t*)(ws + off); off += (size_t)Ttot * D_DIM * 2;  // 8 MiB
  ushort_t* TT = (ushort_t*)(ws + off); off += (size_t)Ttot * D_DIM * 2;  // 8 MiB
  float* nrm = (float*)(ws + off); off += (size_t)Ttot * 4;
  float* sg  = (float*)(ws + off); off += (size_t)Bn * 4;
  float* sp  = (float*)(ws + off); off += (size_t)Bn * 4;
  float* Mg  = (float*)(ws + off); off += (size_t)Bn * D_DIM * 4;         // 8 MiB
  off = (off + 4095) & ~(size_t)4095;
  ushort_t* Kq = (ushort_t*)(ws + off); off += (size_t)Bn * QW * 2;       // 64 MiB

  // guard: if workspace is too small, leave out = 0 (clean absmax-fail signature)
  if (ws_size < off) return;

  hipMemsetAsync(sg, 0, (size_t)Bn * 2 * sizeof(float), stream);  // sg+sp contiguous
  hipMemsetAsync(Mg, 0, (size_t)Bn * D_DIM * sizeof(float), stream);

  prep_cast<<<Ttot, 256, 0, stream>>>(G, P, Tb, nrm, Bn);
  prep_transpose<<<dim3(Ttot / 64, D_DIM / 64), 256, 0, stream>>>(Tb, TT, Ttot);

  // quarters 0,1: gen half (j in [0,8192)) -> Mg, sg.  2,3: pos half -> out scaled by sg, sp.
  for (int q = 0; q < 4; q++) {
    const int j_origin = q * QW;
    const bool genq = (q < 2);
    phase1_kernel<<<dim3(Bn / 128, QW / 128), 256, 0, stream>>>(
        Tb, nrm, Kq, genq ? sg : sp, j_origin, genq ? 1 : 0);
    phase2_kernel<<<dim3(Bn / 64, 4), 256, 0, stream>>>(
        Kq, TT, genq ? (const float*)nullptr : sg, genq ? Mg : out, j_origin, Ttot);
  }

  combine_kernel<<<Bn, 256, 0, stream>>>(out, Mg, sp);
}

// Round 3
// 420.700 us; speedup vs baseline: 1.2328x; 1.2328x over previous
//
#include <hip/hip_runtime.h>
#include <stdint.h>

#define D_DIM 256
#define BI 64        // i-rows per block
#define TJ 256       // j-tile
#define CHUNK 4096   // j per block

typedef unsigned short ushort_t;
typedef __attribute__((ext_vector_type(8))) short bf16x8;   // 8 bf16 = 4 VGPRs
typedef __attribute__((ext_vector_type(4))) float f32x4;

__device__ __forceinline__ unsigned short f2bf(float f) {
  union { float f; unsigned u; } x; x.f = f;
  unsigned r = x.u + 0x7FFFu + ((x.u >> 16) & 1u);  // round-nearest-even
  return (unsigned short)(r >> 16);
}

// async global->LDS, 16B per lane. LDS dest = wave-uniform base + lane*16.
__device__ __forceinline__ void g2l16(const void* g, void* l) {
  __builtin_amdgcn_global_load_lds(
      (__attribute__((address_space(1))) void*)(uintptr_t)g,
      (__attribute__((address_space(3))) void*)(unsigned)(uintptr_t)l,
      16, 0, 0);
}

// ---------------- prep: cast fp32 -> bf16 rows + row norms ----------------
__global__ __launch_bounds__(256) void
prep_cast(const float* __restrict__ G, const float* __restrict__ P,
          ushort_t* __restrict__ Tb, float* __restrict__ nrm, int Bn)
{
  const int r = blockIdx.x, t = threadIdx.x;
  const float* src = (r < Bn) ? (G + (size_t)r * D_DIM)
                              : (P + (size_t)(r - Bn) * D_DIM);
  float v = src[t];
  Tb[(size_t)r * D_DIM + t] = f2bf(v);
  float s = v * v;
  #pragma unroll
  for (int o = 32; o > 0; o >>= 1) s += __shfl_down(s, o, 64);
  __shared__ float red[4];
  if ((t & 63) == 0) red[t >> 6] = s;
  __syncthreads();
  if (t == 0) nrm[r] = red[0] + red[1] + red[2] + red[3];
}

// ---------------- prep: transpose Tb (Ttot x 256) -> TT (256 x Ttot) ----------------
__global__ __launch_bounds__(256) void
prep_transpose(const ushort_t* __restrict__ Tb, ushort_t* __restrict__ TT, int Ttot)
{
  __shared__ ushort_t Ts[64][72];
  const int t = threadIdx.x;
  const int j0 = blockIdx.x * 64, d0 = blockIdx.y * 64;
  #pragma unroll
  for (int q = 0; q < 16; q++) {
    int idx = q * 256 + t;
    int jr = idx >> 6, dc = idx & 63;
    Ts[dc][jr] = Tb[(size_t)(j0 + jr) * D_DIM + d0 + dc];
  }
  __syncthreads();
  #pragma unroll
  for (int q = 0; q < 16; q++) {
    int idx = q * 256 + t;
    int dr = idx >> 6, jc = idx & 63;
    TT[(size_t)(d0 + dr) * Ttot + j0 + jc] = Ts[dr][jc];
  }
}

// ---------------- fused: S^T -> kv (LDS) -> O^T accumulate ----------------
// Block: 256 thr / 4 waves. i-tile = 64 rows; j-chunk = 4096 (16 tiles of 256).
// GEMM1: S^T[j256][i64] (wave w owns j64 quarter); epilogue -> kv bf16 in Ksm[i][j].
// GEMM2: O^T[d256][i64] += TT[d][j] * kv (wave w owns d64 quarter), acc in regs.
// End: rowsum partials -> atomicAdd(sg/sp); O^T -> atomicAdd(Og/Op).
__global__ __launch_bounds__(256, 2) void
fused_kernel(const ushort_t* __restrict__ Tb, const ushort_t* __restrict__ TT,
             const float* __restrict__ nrm, float* __restrict__ sg,
             float* __restrict__ sp, float* __restrict__ Og,
             float* __restrict__ Op, int Bn, int Ttot)
{
  __shared__ ushort_t Asm[256 * 32];    // T rows (j) x 32 d    16 KB
  __shared__ ushort_t Gsm[64 * 32];     // G rows (i) x 32 d     4 KB
  __shared__ ushort_t TTsm[256 * 32];   // TT rows (d) x 32 j   16 KB
  __shared__ ushort_t Ksm[64 * 264];    // kv [i][256+8pad]     33 KB

  const int t = threadIdx.x;
  const int w = t >> 6, lane = t & 63;
  const int q = lane >> 4, c = lane & 15;
  const int i0 = blockIdx.x * BI;
  const int chunk0 = blockIdx.y * CHUNK;
  const bool gen = (chunk0 < Bn);

  f32x4 accO[4][4];
  #pragma unroll
  for (int m = 0; m < 4; m++)
    #pragma unroll
    for (int n = 0; n < 4; n++) accO[m][n] = (f32x4)0.f;
  float rs[4] = {0.f, 0.f, 0.f, 0.f};
  float ni[4];
  #pragma unroll
  for (int nt = 0; nt < 4; nt++) ni[nt] = nrm[i0 + nt * 16 + c];

  const int srow = t >> 2;        // 0..63
  const int scol = (t & 3) * 8;   // 0,8,16,24

  for (int jt = 0; jt < CHUNK; jt += TJ) {
    const int j0 = chunk0 + jt;
    f32x4 acc1[4][4];
    #pragma unroll
    for (int m = 0; m < 4; m++)
      #pragma unroll
      for (int n = 0; n < 4; n++) acc1[m][n] = (f32x4)0.f;

    // ---- GEMM1: S^T over d = 256 (8 steps of 32) ----
    for (int ds = 0; ds < 8; ds++) {
      const ushort_t* asrc = Tb + (size_t)(j0 + srow) * D_DIM + ds * 32 + scol;
      g2l16(asrc,                 Asm + t * 8);
      g2l16(asrc + 64 * D_DIM,    Asm + 2048 + t * 8);
      g2l16(asrc + 128 * D_DIM,   Asm + 4096 + t * 8);
      g2l16(asrc + 192 * D_DIM,   Asm + 6144 + t * 8);
      g2l16(Tb + (size_t)(i0 + srow) * D_DIM + ds * 32 + scol, Gsm + t * 8);
      __syncthreads();
      bf16x8 af[4], bf[4];
      #pragma unroll
      for (int mt = 0; mt < 4; mt++)
        af[mt] = *(const bf16x8*)&Asm[(w * 64 + mt * 16 + c) * 32 + q * 8];
      #pragma unroll
      for (int nt = 0; nt < 4; nt++)
        bf[nt] = *(const bf16x8*)&Gsm[(nt * 16 + c) * 32 + q * 8];
      #pragma unroll
      for (int mt = 0; mt < 4; mt++)
        #pragma unroll
        for (int nt = 0; nt < 4; nt++)
          acc1[mt][nt] = __builtin_amdgcn_mfma_f32_16x16x32_bf16(af[mt], bf[nt], acc1[mt][nt], 0, 0, 0);
      __syncthreads();
    }

    // ---- epilogue: kv = exp(-dist/20), rowsum, pack -> Ksm ----
    #pragma unroll
    for (int mt = 0; mt < 4; mt++) {
      const int jb = j0 + w * 64 + mt * 16 + q * 4;   // global j of reg 0
      const float4 njv = *(const float4*)&nrm[jb];
      const float nj[4] = {njv.x, njv.y, njv.z, njv.w};
      #pragma unroll
      for (int nt = 0; nt < 4; nt++) {
        const int ig = i0 + nt * 16 + c;
        uint32_t pb[4];
        #pragma unroll
        for (int reg = 0; reg < 4; reg++) {
          float sq = ni[nt] + nj[reg] - 2.f * acc1[mt][nt][reg];
          float dd = sqrtf(fmaxf(sq, 0.f));
          float kv = __expf(dd * -0.05f);
          if (gen && (jb + reg == ig)) kv = 0.f;
          rs[nt] += kv;
          union { float f; uint32_t u; } uu; uu.f = kv; pb[reg] = uu.u;
        }
        uint2 pk;  // truncating bf16 pack: 1 v_perm per pair
        pk.x = __builtin_amdgcn_perm(pb[1], pb[0], 0x07060302u);
        pk.y = __builtin_amdgcn_perm(pb[3], pb[2], 0x07060302u);
        *(uint2*)&Ksm[(nt * 16 + c) * 264 + w * 64 + mt * 16 + q * 4] = pk;
      }
    }
    __syncthreads();   // Ksm visible to all waves

    // ---- GEMM2: O^T += TT[d][j256] * kv  (8 k-steps of 32 j) ----
    for (int ks = 0; ks < 8; ks++) {
      const ushort_t* tsrc = TT + (size_t)srow * Ttot + j0 + ks * 32 + scol;
      g2l16(tsrc,                        TTsm + t * 8);
      g2l16(tsrc + (size_t)64 * Ttot,    TTsm + 2048 + t * 8);
      g2l16(tsrc + (size_t)128 * Ttot,   TTsm + 4096 + t * 8);
      g2l16(tsrc + (size_t)192 * Ttot,   TTsm + 6144 + t * 8);
      __syncthreads();
      bf16x8 af[4], kf[4];
      #pragma unroll
      for (int mt = 0; mt < 4; mt++)
        af[mt] = *(const bf16x8*)&TTsm[(w * 64 + mt * 16 + c) * 32 + q * 8];
      #pragma unroll
      for (int nt = 0; nt < 4; nt++)
        kf[nt] = *(const bf16x8*)&Ksm[(nt * 16 + c) * 264 + ks * 32 + q * 8];
      #pragma unroll
      for (int mt = 0; mt < 4; mt++)
        #pragma unroll
        for (int nt = 0; nt < 4; nt++)
          accO[mt][nt] = __builtin_amdgcn_mfma_f32_16x16x32_bf16(af[mt], kf[nt], accO[mt][nt], 0, 0, 0);
      __syncthreads();
    }
  }

  // rowsum partials -> sg/sp
  float* S = gen ? sg : sp;
  #pragma unroll
  for (int nt = 0; nt < 4; nt++) {
    float r = rs[nt];
    r += __shfl_xor(r, 16, 64);
    r += __shfl_xor(r, 32, 64);
    if (lane < 16) atomicAdd(&S[i0 + nt * 16 + lane], r);
  }
  // O^T partials -> Og/Op   (D row m = q*4+reg -> d; col n = c -> i)
  float* O = gen ? Og : Op;
  #pragma unroll
  for (int mt = 0; mt < 4; mt++)
    #pragma unroll
    for (int nt = 0; nt < 4; nt++)
      #pragma unroll
      for (int reg = 0; reg < 4; reg++) {
        const int d = w * 64 + mt * 16 + q * 4 + reg;
        const int ig = i0 + nt * 16 + c;
        atomicAdd(&O[(size_t)ig * D_DIM + d], accO[mt][nt][reg]);
      }
}

// ---------------- combine: out = sg*Op - sp*Og ----------------
__global__ __launch_bounds__(256) void
combine_kernel(float* __restrict__ out, const float* __restrict__ Og,
               const float* __restrict__ Op, const float* __restrict__ sg,
               const float* __restrict__ sp)
{
  const int i = blockIdx.x, t = threadIdx.x;
  const size_t idx = (size_t)i * D_DIM + t;
  out[idx] = sg[i] * Op[idx] - sp[i] * Og[idx];
}

extern "C" void kernel_launch(void* const* d_in, const int* in_sizes, int n_in,
                              void* d_out, int out_size, void* d_ws, size_t ws_size,
                              hipStream_t stream)
{
  const float* G = (const float*)d_in[0];
  const float* P = (const float*)d_in[1];
  const int Bn = in_sizes[0] / D_DIM;   // 8192
  const int Xn = in_sizes[1] / D_DIM;   // 8192
  const int Ttot = Bn + Xn;             // 16384

  // workspace (~33.7 MiB)
  uint8_t* ws = (uint8_t*)d_ws;
  size_t off = 0;
  ushort_t* Tb = (ushort_t*)(ws + off); off += (size_t)Ttot * D_DIM * 2;  // 8 MiB
  ushort_t* TT = (ushort_t*)(ws + off); off += (size_t)Ttot * D_DIM * 2;  // 8 MiB
  float* nrm = (float*)(ws + off); off += (size_t)Ttot * 4;
  float* sg  = (float*)(ws + off); off += (size_t)Bn * 4;
  float* sp  = (float*)(ws + off); off += (size_t)Bn * 4;
  float* Og  = (float*)(ws + off); off += (size_t)Bn * D_DIM * 4;         // 8 MiB
  float* Op  = (float*)(ws + off); off += (size_t)Bn * D_DIM * 4;         // 8 MiB
  if (ws_size < off) return;  // clean-fail signature if ws too small

  // zero sg..Op in one contiguous memset
  hipMemsetAsync(sg, 0, (size_t)Bn * (2 + 2 * D_DIM) * sizeof(float), stream);

  prep_cast<<<Ttot, 256, 0, stream>>>(G, P, Tb, nrm, Bn);
  prep_transpose<<<dim3(Ttot / 64, D_DIM / 64), 256, 0, stream>>>(Tb, TT, Ttot);
  fused_kernel<<<dim3(Bn / BI, Ttot / CHUNK), 256, 0, stream>>>(
      Tb, TT, nrm, sg, sp, Og, Op, Bn, Ttot);
  combine_kernel<<<Bn, 256, 0, stream>>>((float*)d_out, Og, Op, sg, sp);
}